// Round 4
// baseline (772.584 us; speedup 1.0000x reference)
//
#include <hip/hip_runtime.h>
#include <hip/hip_bf16.h>
#include <cstdint>
#include <cstddef>

typedef __bf16 bf16_t;
typedef bf16_t bf16x8 __attribute__((ext_vector_type(8)));
typedef bf16_t bf16x4v __attribute__((ext_vector_type(4)));
typedef float floatx4 __attribute__((ext_vector_type(4)));

static constexpr int B_ = 8192;   // batch
static constexpr int H_ = 1024;   // hidden
static constexpr int G4 = 4096;   // 4*H
static constexpr int K_ = 1024;   // input size == hidden size

// lgkmcnt(0)-only wait (vmcnt=63, expcnt=7 -> no wait), then raw s_barrier.
// __syncthreads would drain vmcnt(0), killing the in-flight prefetch loads.
// Outstanding global loads target private VGPRs -> no cross-wave hazard.
__device__ inline void pipeline_barrier() {
  __builtin_amdgcn_s_waitcnt(0xC07F);  // vmcnt[3:0]=F,[15:14]=3; exp=7; lgkm=0
  __builtin_amdgcn_s_barrier();
}

// ---------------- one cast dispatch: input+hx plain, weights gate-permuted --
__global__ __launch_bounds__(256) void cast_all(
    const float* __restrict__ input, const float* __restrict__ hx,
    const float* __restrict__ wih, const float* __restrict__ whh,
    bf16_t* __restrict__ Abf, bf16_t* __restrict__ Hbf,
    bf16_t* __restrict__ Wib, bf16_t* __restrict__ Whb) {
  const int bb = blockIdx.x;
  const int tid = threadIdx.x;
  if (bb < 8192) {               // plain cast, 8 elems/thread
    const float* src = (bb < 4096) ? input : hx;
    bf16_t* dst      = (bb < 4096) ? Abf : Hbf;
    const int idx = (bb & 4095) * 256 + tid;
    const float4 v0 = ((const float4*)src)[idx * 2];
    const float4 v1 = ((const float4*)src)[idx * 2 + 1];
    bf16x8 o;
    o[0] = (bf16_t)v0.x; o[1] = (bf16_t)v0.y; o[2] = (bf16_t)v0.z; o[3] = (bf16_t)v0.w;
    o[4] = (bf16_t)v1.x; o[5] = (bf16_t)v1.y; o[6] = (bf16_t)v1.z; o[7] = (bf16_t)v1.w;
    ((bf16x8*)dst)[idx] = o;
  } else {                       // weight row permute: out row h*4+g <- g*1024+h
    const int rp = bb & 4095;
    const float* src = (bb < 12288) ? wih : whh;
    bf16_t*      dst = (bb < 12288) ? Wib : Whb;
    const int h = rp >> 2, g = rp & 3;
    const int rin = g * 1024 + h;
    const int c = tid * 4;
    const float4 v = *(const float4*)(src + (size_t)rin * K_ + c);
    bf16x4v o;
    o[0] = (bf16_t)v.x; o[1] = (bf16_t)v.y; o[2] = (bf16_t)v.z; o[3] = (bf16_t)v.w;
    *(bf16x4v*)(dst + (size_t)rp * K_ + c) = o;
  }
}

// ---------------- dual GEMM: C = A * W^T (both K-major), bf16 in/out --------
// Register-staged single-barrier pipeline (AITER-style):
//   iter k: ds_read frags buf[k&1] | issue loads T(k+2)->Q | 16 MFMA
//           | ds_write buf[1-(k&1)] <- P (T(k+1), fine-grained vmcnt)
//           | lgkm-only barrier.
// LDS XOR swizzle kept from R3 (conflict-free frag reads).
__global__ __launch_bounds__(256) void gemm_bt_dual(
    const bf16_t* __restrict__ A0, const bf16_t* __restrict__ A1,
    const bf16_t* __restrict__ W0, const bf16_t* __restrict__ W1,
    bf16_t* __restrict__ C0, bf16_t* __restrict__ C1) {
  constexpr int N = G4, K = K_;
  const bf16_t* A = blockIdx.z ? A1 : A0;
  const bf16_t* W = blockIdx.z ? W1 : W0;
  bf16_t*       C = blockIdx.z ? C1 : C0;

  __shared__ bf16_t As[2][128 * 32];
  __shared__ bf16_t Bs[2][128 * 32];

  const int tid  = threadIdx.x;
  const int lane = tid & 63;
  const int wid  = tid >> 6;
  const int wm   = wid >> 1, wn = wid & 1;
  const int lrow = lane & 15, quad = lane >> 4;

  const int m0 = blockIdx.y * 128;
  const int n0 = blockIdx.x * 128;

  // chunk L (16B) of a tile lives at byte L*16; global source chunk is
  // ((L&3) ^ ((L>>3)&3)) of row L>>2  (XOR swizzle)
  const int L0 = tid;
  const int L1 = 256 + tid;
  const int c0 = (((L0 & 3) ^ ((L0 >> 3) & 3))) * 8;
  const int c1 = (((L1 & 3) ^ ((L1 >> 3) & 3))) * 8;
  const bf16_t* gA0 = A + (size_t)(m0 + (L0 >> 2)) * K + c0;
  const bf16_t* gA1 = A + (size_t)(m0 + (L1 >> 2)) * K + c1;
  const bf16_t* gB0 = W + (size_t)(n0 + (L0 >> 2)) * K + c0;
  const bf16_t* gB1 = W + (size_t)(n0 + (L1 >> 2)) * K + c1;

  // fragment-read chunk after swizzle
  const int qc = (quad ^ ((lrow >> 1) & 3)) * 8;

  uint4 R0[4], R1[4];   // two prefetch register sets: [A0,A1,B0,B1]

#define GLOAD(R, kofs)                                   \
  do {                                                   \
    (R)[0] = *(const uint4*)(gA0 + (kofs));              \
    (R)[1] = *(const uint4*)(gA1 + (kofs));              \
    (R)[2] = *(const uint4*)(gB0 + (kofs));              \
    (R)[3] = *(const uint4*)(gB1 + (kofs));              \
  } while (0)

#define LDSWRITE(buf, R)                                                  \
  do {                                                                    \
    *(uint4*)((char*)&As[buf][0] + tid * 16)        = (R)[0];             \
    *(uint4*)((char*)&As[buf][0] + 4096 + tid * 16) = (R)[1];             \
    *(uint4*)((char*)&Bs[buf][0] + tid * 16)        = (R)[2];             \
    *(uint4*)((char*)&Bs[buf][0] + 4096 + tid * 16) = (R)[3];             \
  } while (0)

  floatx4 acc[4][4] = {};
  bf16x8 af[4], bfr[4];

#define FRAGREAD(buf)                                                          \
  do {                                                                         \
    _Pragma("unroll") for (int i = 0; i < 4; ++i)                              \
        af[i] = *(const bf16x8*)&As[buf][(wm * 64 + i * 16 + lrow) * 32 + qc]; \
    _Pragma("unroll") for (int j = 0; j < 4; ++j)                              \
        bfr[j] = *(const bf16x8*)&Bs[buf][(wn * 64 + j * 16 + lrow) * 32 + qc];\
  } while (0)

#define MFMA16()                                                               \
  do {                                                                         \
    _Pragma("unroll") for (int i = 0; i < 4; ++i)                              \
        _Pragma("unroll") for (int j = 0; j < 4; ++j)                          \
            acc[i][j] = __builtin_amdgcn_mfma_f32_16x16x32_bf16(               \
                af[i], bfr[j], acc[i][j], 0, 0, 0);                            \
  } while (0)

  // prologue: T0 -> LDS buf0; T1 -> R0
  GLOAD(R0, 0);
  LDSWRITE(0, R0);
  GLOAD(R0, 32);
  pipeline_barrier();

  // 15 pairs: iters k = 0..29, all prefetching
  for (int k2 = 0; k2 < 15; ++k2) {
    const int kb = k2 * 64;
    // even iter (buf 0); P=R0 (T k+1), prefetch T(k+2)->R1
    FRAGREAD(0);
    GLOAD(R1, kb + 64);
    MFMA16();
    LDSWRITE(1, R0);
    pipeline_barrier();
    // odd iter (buf 1); P=R1, prefetch ->R0
    FRAGREAD(1);
    GLOAD(R0, kb + 96);
    MFMA16();
    LDSWRITE(0, R1);
    pipeline_barrier();
  }
  // tail pair: k=30 (write T31 from R0), k=31
  FRAGREAD(0);
  MFMA16();
  LDSWRITE(1, R0);
  pipeline_barrier();
  FRAGREAD(1);
  MFMA16();

#undef GLOAD
#undef LDSWRITE
#undef FRAGREAD
#undef MFMA16

  // C/D layout (m89-verified): col(n)=lane&15, row(m)=quad*4+reg
#pragma unroll
  for (int i = 0; i < 4; ++i) {
    const int mbase = m0 + wm * 64 + i * 16 + quad * 4;
#pragma unroll
    for (int j = 0; j < 4; ++j) {
      const int n = n0 + wn * 64 + j * 16 + lrow;
#pragma unroll
      for (int r = 0; r < 4; ++r)
        C[(size_t)(mbase + r) * N + n] = (bf16_t)acc[i][j][r];
    }
  }
}

// ---------------- fused epilogue, gate-interleaved layout --------------------
__device__ inline float sigmoid_f(float x) { return 1.0f / (1.0f + __expf(-x)); }
__device__ inline float tanh_f(float x) {
  float e = __expf(2.0f * x);
  return 1.0f - 2.0f / (e + 1.0f);   // safe at +/-inf
}

__global__ __launch_bounds__(256) void ln_lstm_epilogue(
    const bf16_t* __restrict__ IG, const bf16_t* __restrict__ HG,
    const float* __restrict__ cx,
    const float* __restrict__ wi, const float* __restrict__ bi,
    const float* __restrict__ wh, const float* __restrict__ bh,
    const float* __restrict__ wc, const float* __restrict__ bc,
    float* __restrict__ hy_out, float* __restrict__ cy_out) {
  const int b = blockIdx.x;
  const int t = threadIdx.x;
  const int lane = t & 63;
  const int wid = t >> 6;

  __shared__ float red1[4][4];
  __shared__ float red2[4][2];

  const bf16x8 ig0 = *(const bf16x8*)(IG + (size_t)b * 4096 + t * 16);
  const bf16x8 ig1 = *(const bf16x8*)(IG + (size_t)b * 4096 + t * 16 + 8);
  const bf16x8 hg0 = *(const bf16x8*)(HG + (size_t)b * 4096 + t * 16);
  const bf16x8 hg1 = *(const bf16x8*)(HG + (size_t)b * 4096 + t * 16 + 8);
  const float4 cx4 = *(const float4*)(cx + (size_t)b * 1024 + t * 4);

  float vi[16], vh[16];
#pragma unroll
  for (int e = 0; e < 8; ++e) {
    vi[e] = (float)ig0[e]; vi[8 + e] = (float)ig1[e];
    vh[e] = (float)hg0[e]; vh[8 + e] = (float)hg1[e];
  }
  float si = 0, qi = 0, sh = 0, qh = 0;
#pragma unroll
  for (int k = 0; k < 16; ++k) {
    si += vi[k]; qi = fmaf(vi[k], vi[k], qi);
    sh += vh[k]; qh = fmaf(vh[k], vh[k], qh);
  }
#pragma unroll
  for (int off = 32; off; off >>= 1) {
    si += __shfl_down(si, off); qi += __shfl_down(qi, off);
    sh += __shfl_down(sh, off); qh += __shfl_down(qh, off);
  }
  if (lane == 0) { red1[wid][0] = si; red1[wid][1] = qi; red1[wid][2] = sh; red1[wid][3] = qh; }
  __syncthreads();
  si = red1[0][0] + red1[1][0] + red1[2][0] + red1[3][0];
  qi = red1[0][1] + red1[1][1] + red1[2][1] + red1[3][1];
  sh = red1[0][2] + red1[1][2] + red1[2][2] + red1[3][2];
  qh = red1[0][3] + red1[1][3] + red1[2][3] + red1[3][3];

  const float invN = 1.0f / 4096.0f;
  const float mui = si * invN, muh = sh * invN;
  const float rsi = rsqrtf(fmaxf(qi * invN - mui * mui, 0.0f) + 1e-5f);
  const float rsh = rsqrtf(fmaxf(qh * invN - muh * muh, 0.0f) + 1e-5f);

  // LN params in ORIGINAL layout: index g*1024 + h, h = 4t..4t+3 -> float4
  float4 wig[4], big[4], whg[4], bhg[4];
#pragma unroll
  for (int g = 0; g < 4; ++g) {
    wig[g] = *(const float4*)(wi + g * 1024 + t * 4);
    big[g] = *(const float4*)(bi + g * 1024 + t * 4);
    whg[g] = *(const float4*)(wh + g * 1024 + t * 4);
    bhg[g] = *(const float4*)(bh + g * 1024 + t * 4);
  }

  const float cxa[4] = {cx4.x, cx4.y, cx4.z, cx4.w};
  float cv[4], ov[4];
  float sc = 0, qc2 = 0;
#pragma unroll
  for (int j = 0; j < 4; ++j) {
    const float wg[4] = {((const float*)&wig[0])[j], ((const float*)&wig[1])[j],
                         ((const float*)&wig[2])[j], ((const float*)&wig[3])[j]};
    const float bg[4] = {((const float*)&big[0])[j], ((const float*)&big[1])[j],
                         ((const float*)&big[2])[j], ((const float*)&big[3])[j]};
    const float wg2[4] = {((const float*)&whg[0])[j], ((const float*)&whg[1])[j],
                          ((const float*)&whg[2])[j], ((const float*)&whg[3])[j]};
    const float bg2[4] = {((const float*)&bhg[0])[j], ((const float*)&bhg[1])[j],
                          ((const float*)&bhg[2])[j], ((const float*)&bhg[3])[j]};
    float G[4];
#pragma unroll
    for (int g = 0; g < 4; ++g) {
      const int e = j * 4 + g;   // n' = 16t + e  ->  h = 4t+j, gate g
      G[g] = (vi[e] - mui) * rsi * wg[g] + bg[g] +
             (vh[e] - muh) * rsh * wg2[g] + bg2[g];
    }
    const float in_g = sigmoid_f(G[0]);
    const float fo_g = sigmoid_f(G[1]);
    const float ce_g = tanh_f(G[2]);
    ov[j] = sigmoid_f(G[3]);
    const float c = fo_g * cxa[j] + in_g * ce_g;
    cv[j] = c;
    sc += c; qc2 = fmaf(c, c, qc2);
  }
#pragma unroll
  for (int off = 32; off; off >>= 1) {
    sc += __shfl_down(sc, off); qc2 += __shfl_down(qc2, off);
  }
  if (lane == 0) { red2[wid][0] = sc; red2[wid][1] = qc2; }
  __syncthreads();
  sc = red2[0][0] + red2[1][0] + red2[2][0] + red2[3][0];
  qc2 = red2[0][1] + red2[1][1] + red2[2][1] + red2[3][1];
  const float invH = 1.0f / 1024.0f;
  const float muc = sc * invH;
  const float rsc = rsqrtf(fmaxf(qc2 * invH - muc * muc, 0.0f) + 1e-5f);

  const float4 wc4 = ((const float4*)wc)[t];
  const float4 bc4 = ((const float4*)bc)[t];
  const float wca[4] = {wc4.x, wc4.y, wc4.z, wc4.w};
  const float bca[4] = {bc4.x, bc4.y, bc4.z, bc4.w};
  float4 hyv, cyv;
#pragma unroll
  for (int j = 0; j < 4; ++j) {
    const float cyn = (cv[j] - muc) * rsc * wca[j] + bca[j];
    ((float*)&cyv)[j] = cyn;
    ((float*)&hyv)[j] = ov[j] * tanh_f(cyn);
  }
  *(float4*)(cy_out + (size_t)b * 1024 + t * 4) = cyv;
  *(float4*)(hy_out + (size_t)b * 1024 + t * 4) = hyv;
}

extern "C" void kernel_launch(void* const* d_in, const int* in_sizes, int n_in,
                              void* d_out, int out_size, void* d_ws, size_t ws_size,
                              hipStream_t stream) {
  const float* input  = (const float*)d_in[0];
  const float* hx     = (const float*)d_in[1];
  const float* cx     = (const float*)d_in[2];
  const float* w_ih   = (const float*)d_in[3];
  const float* w_hh   = (const float*)d_in[4];
  const float* ln_i_w = (const float*)d_in[5];
  const float* ln_i_b = (const float*)d_in[6];
  const float* ln_h_w = (const float*)d_in[7];
  const float* ln_h_b = (const float*)d_in[8];
  const float* ln_c_w = (const float*)d_in[9];
  const float* ln_c_b = (const float*)d_in[10];

  float* out = (float*)d_out;
  float* hy = out;
  float* cy = out + (size_t)B_ * H_;

  // workspace (bf16): A 16MB | H 16MB | Wih 8MB | Whh 8MB | IG 64MB | HG 64MB
  bf16_t* Abf = (bf16_t*)d_ws;
  bf16_t* Hbf = Abf + (size_t)B_ * K_;
  bf16_t* Wib = Hbf + (size_t)B_ * K_;
  bf16_t* Whb = Wib + (size_t)G4 * K_;
  bf16_t* IG  = Whb + (size_t)G4 * K_;
  bf16_t* HG  = IG + (size_t)B_ * G4;

  cast_all<<<16384, 256, 0, stream>>>(input, hx, w_ih, w_hh, Abf, Hbf, Wib, Whb);

  gemm_bt_dual<<<dim3(G4 / 128, B_ / 128, 2), 256, 0, stream>>>(Abf, Hbf, Wib, Whb, IG, HG);

  ln_lstm_epilogue<<<B_, 256, 0, stream>>>(IG, HG, cx, ln_i_w, ln_i_b,
                                           ln_h_w, ln_h_b, ln_c_w, ln_c_b, hy, cy);
}